// Round 2
// baseline (914.312 us; speedup 1.0000x reference)
//
#include <hip/hip_runtime.h>
#include <hip/hip_bf16.h>

typedef unsigned short u16;
typedef __attribute__((ext_vector_type(8))) short bf16x8;
typedef __attribute__((ext_vector_type(4))) float f32x4;

#define BM 128
#define BN 128
#define BK 32
#define LDT 40  // padded LDS inner stride (32 + 8, keeps 16B alignment)

__device__ __forceinline__ u16 f2bf(float f) {
  union { float f; unsigned u; } a; a.f = f;
  unsigned r = a.u + 0x7fffu + ((a.u >> 16) & 1u);  // RNE
  return (u16)(r >> 16);
}

// Stage a [128 rows x 32 inner] tile where global rows are the 128-dim.
__device__ __forceinline__ void stage_direct(const u16* __restrict__ g, int ldg,
                                             u16* __restrict__ s, int tid) {
#pragma unroll
  for (int c = 0; c < 2; ++c) {
    int ci = tid + c * 256;
    int row = ci >> 2, koff = (ci & 3) << 3;
    uint4 v = *(const uint4*)(g + (long)row * ldg + koff);
    *(uint4*)(s + row * LDT + koff) = v;
  }
}

// Stage a tile stored as [32 rows x 128 contiguous] into LDS [128][32] (transposed).
__device__ __forceinline__ void stage_transpose(const u16* __restrict__ g, int ldg,
                                                u16* __restrict__ s, int tid) {
#pragma unroll
  for (int c = 0; c < 2; ++c) {
    int ci = tid + c * 256;
    int row = ci >> 4, noff = (ci & 15) << 3;
    uint4 v = *(const uint4*)(g + (long)row * ldg + noff);
    u16 tmp[8];
    *(uint4*)tmp = v;
#pragma unroll
    for (int j = 0; j < 8; ++j) s[(noff + j) * LDT + row] = tmp[j];
  }
}

// C[m][n] = sum_k A[m][k]*B[k][n] (logical). TSA: A stored [K][M]. TSB: B stored [N][K].
template <bool TSA, bool TSB, bool OUT_BF16, bool RESID>
__global__ __launch_bounds__(256) void gemm_kernel(
    const u16* __restrict__ Ag, const u16* __restrict__ Bg, void* __restrict__ Cg,
    const float* __restrict__ bias, const float* __restrict__ resid,
    int lda, int ldb, int ldc,
    long strideA, long strideB, long strideC, int K, float scale) {
  __shared__ u16 As[BM * LDT];
  __shared__ u16 Bs[BN * LDT];
  int tid = threadIdx.x;
  int b = blockIdx.z;
  int m0 = blockIdx.y * BM, n0 = blockIdx.x * BN;
  const u16* Ab = Ag + (long)b * strideA;
  const u16* Bb = Bg + (long)b * strideB;
  int wave = tid >> 6, lane = tid & 63;
  int wr = wave >> 1, wc = wave & 1;
  int lrow = lane & 15, quad = lane >> 4;

  f32x4 acc[4][4];
#pragma unroll
  for (int i = 0; i < 4; ++i)
#pragma unroll
    for (int j = 0; j < 4; ++j) acc[i][j] = (f32x4){0.f, 0.f, 0.f, 0.f};

  for (int k0 = 0; k0 < K; k0 += BK) {
    if (TSA) stage_transpose(Ab + (long)k0 * lda + m0, lda, As, tid);
    else     stage_direct(Ab + (long)m0 * lda + k0, lda, As, tid);
    if (TSB) stage_direct(Bb + (long)n0 * ldb + k0, ldb, Bs, tid);
    else     stage_transpose(Bb + (long)k0 * ldb + n0, ldb, Bs, tid);
    __syncthreads();
    bf16x8 af[4], bfr[4];
#pragma unroll
    for (int mt = 0; mt < 4; ++mt)
      af[mt] = *(const bf16x8*)&As[(wr * 64 + mt * 16 + lrow) * LDT + quad * 8];
#pragma unroll
    for (int nt = 0; nt < 4; ++nt)
      bfr[nt] = *(const bf16x8*)&Bs[(wc * 64 + nt * 16 + lrow) * LDT + quad * 8];
#pragma unroll
    for (int mt = 0; mt < 4; ++mt)
#pragma unroll
      for (int nt = 0; nt < 4; ++nt)
        acc[mt][nt] = __builtin_amdgcn_mfma_f32_16x16x32_bf16(af[mt], bfr[nt], acc[mt][nt], 0, 0, 0);
    __syncthreads();
  }

  long cbase = (long)b * strideC;
#pragma unroll
  for (int mt = 0; mt < 4; ++mt) {
#pragma unroll
    for (int r = 0; r < 4; ++r) {
      int row = m0 + wr * 64 + mt * 16 + quad * 4 + r;
      float bv = bias ? bias[row] : 0.f;
#pragma unroll
      for (int nt = 0; nt < 4; ++nt) {
        int col = n0 + wc * 64 + nt * 16 + lrow;
        long idx = cbase + (long)row * ldc + col;
        float val = acc[mt][nt][r] * scale + bv;
        if (RESID) val += resid[idx];
        if (OUT_BF16) ((u16*)Cg)[idx] = f2bf(val);
        else ((float*)Cg)[idx] = val;
      }
    }
  }
}

// One block per (group, batch): 32 channels x 1024 spatial, contiguous 32768 floats.
__global__ __launch_bounds__(256) void groupnorm_kernel(
    const float* __restrict__ x, const float* __restrict__ gamma,
    const float* __restrict__ beta, u16* __restrict__ hn) {
  int g = blockIdx.x, b = blockIdx.y;
  const float* xb = x + ((long)b * 512 + g * 32) * 1024;
  int tid = threadIdx.x;
  float s = 0.f, sq = 0.f;
  float4 vals[32];
#pragma unroll
  for (int j = 0; j < 32; ++j) {
    float4 v = *(const float4*)(xb + (long)j * 1024 + tid * 4);
    vals[j] = v;
    s += v.x + v.y + v.z + v.w;
    sq += v.x * v.x + v.y * v.y + v.z * v.z + v.w * v.w;
  }
#pragma unroll
  for (int off = 1; off < 64; off <<= 1) {
    s += __shfl_xor(s, off);
    sq += __shfl_xor(sq, off);
  }
  __shared__ float ls[4], lq[4];
  if ((tid & 63) == 0) { ls[tid >> 6] = s; lq[tid >> 6] = sq; }
  __syncthreads();
  float ts = ls[0] + ls[1] + ls[2] + ls[3];
  float tq = lq[0] + lq[1] + lq[2] + lq[3];
  float mean = ts * (1.f / 32768.f);
  float var = tq * (1.f / 32768.f) - mean * mean;
  float rstd = rsqrtf(var + 1e-6f);
  u16* hb = hn + ((long)b * 512 + g * 32) * 1024;
#pragma unroll
  for (int j = 0; j < 32; ++j) {
    int c = g * 32 + j;
    float ga = gamma[c], be = beta[c];
    float4 v = vals[j];
    float a0 = (v.x - mean) * rstd * ga + be;
    float a1 = (v.y - mean) * rstd * ga + be;
    float a2 = (v.z - mean) * rstd * ga + be;
    float a3 = (v.w - mean) * rstd * ga + be;
    uint2 o;
    o.x = (unsigned)f2bf(a0) | ((unsigned)f2bf(a1) << 16);
    o.y = (unsigned)f2bf(a2) | ((unsigned)f2bf(a3) << 16);
    *(uint2*)(hb + (long)j * 1024 + tid * 4) = o;
  }
}

// One block per score row (1024 fp32). Writes bf16 attn in place at the row start.
__global__ __launch_bounds__(256) void softmax_kernel(float* __restrict__ s) {
  long row = blockIdx.x;
  float* sr = s + row * 1024;
  int tid = threadIdx.x;
  float4 v = *(const float4*)(sr + tid * 4);
  float m = fmaxf(fmaxf(v.x, v.y), fmaxf(v.z, v.w));
#pragma unroll
  for (int off = 1; off < 64; off <<= 1) m = fmaxf(m, __shfl_xor(m, off));
  __shared__ float lm[4], lsum[4];
  if ((tid & 63) == 0) lm[tid >> 6] = m;
  __syncthreads();
  float rowmax = fmaxf(fmaxf(lm[0], lm[1]), fmaxf(lm[2], lm[3]));
  float e0 = expf(v.x - rowmax), e1 = expf(v.y - rowmax);
  float e2 = expf(v.z - rowmax), e3 = expf(v.w - rowmax);
  float sum = e0 + e1 + e2 + e3;
#pragma unroll
  for (int off = 1; off < 64; off <<= 1) sum += __shfl_xor(sum, off);
  if ((tid & 63) == 0) lsum[tid >> 6] = sum;
  __syncthreads();
  float inv = 1.f / (lsum[0] + lsum[1] + lsum[2] + lsum[3]);
  uint2 o;
  o.x = (unsigned)f2bf(e0 * inv) | ((unsigned)f2bf(e1 * inv) << 16);
  o.y = (unsigned)f2bf(e2 * inv) | ((unsigned)f2bf(e3 * inv) << 16);
  *(uint2*)((u16*)sr + tid * 4) = o;
}

// Convert the 4 weight matrices (512x512 fp32) to bf16, packed contiguously.
__global__ __launch_bounds__(256) void convertw_kernel(
    const float* __restrict__ w0, const float* __restrict__ w1,
    const float* __restrict__ w2, const float* __restrict__ w3,
    u16* __restrict__ out) {
  int wsel = blockIdx.x >> 8;
  const float* src = wsel == 0 ? w0 : wsel == 1 ? w1 : wsel == 2 ? w2 : w3;
  int idx = ((blockIdx.x & 255) * 256 + threadIdx.x) * 4;
  float4 v = *(const float4*)(src + idx);
  uint2 o;
  o.x = (unsigned)f2bf(v.x) | ((unsigned)f2bf(v.y) << 16);
  o.y = (unsigned)f2bf(v.z) | ((unsigned)f2bf(v.w) << 16);
  *(uint2*)(out + (long)wsel * 262144 + idx) = o;
}

extern "C" void kernel_launch(void* const* d_in, const int* in_sizes, int n_in,
                              void* d_out, int out_size, void* d_ws, size_t ws_size,
                              hipStream_t stream) {
  const float* x     = (const float*)d_in[0];
  const float* gamma = (const float*)d_in[1];
  const float* beta  = (const float*)d_in[2];
  const float* wq    = (const float*)d_in[3];
  const float* bq    = (const float*)d_in[4];
  const float* wk    = (const float*)d_in[5];
  const float* bk    = (const float*)d_in[6];
  const float* wv    = (const float*)d_in[7];
  const float* bv    = (const float*)d_in[8];
  const float* wp    = (const float*)d_in[9];
  const float* bp    = (const float*)d_in[10];
  float* out = (float*)d_out;
  char* ws = (char*)d_ws;

  // Workspace layout (162 MB total; scores chunked over the query dim)
  u16* wbf = (u16*)ws;                          //   2 MB: wq|wk|wv|wp bf16
  u16* hn  = (u16*)(ws + (2L << 20));           //  32 MB (reused for attn output)
  u16* q   = (u16*)(ws + (34L << 20));          //  32 MB
  u16* kx  = (u16*)(ws + (66L << 20));          //  32 MB
  u16* v   = (u16*)(ws + (98L << 20));          //  32 MB
  float* s = (float*)(ws + (130L << 20));       //  32 MB: [32 b][256 n][1024 m] fp32

  const long SB = 512L * 1024;    // per-batch stride of (512,1024) tensors (u16)
  const long SSC = 256L * 1024;   // per-batch stride of score chunk (fp32)
  const float scale = 0.044194173824159216f;    // 512^-0.5
  const int NCHUNK = 256;

  convertw_kernel<<<1024, 256, 0, stream>>>(wq, wk, wv, wp, wbf);
  groupnorm_kernel<<<dim3(16, 32), 256, 0, stream>>>(x, gamma, beta, hn);

  dim3 gqkv(8, 4, 32);  // N=1024/128, M=512/128, batch
  gemm_kernel<false, false, true, false><<<gqkv, 256, 0, stream>>>(
      wbf + 0 * 262144, hn, q,  bq, nullptr, 512, 1024, 1024, 0, SB, SB, 512, 1.f);
  gemm_kernel<false, false, true, false><<<gqkv, 256, 0, stream>>>(
      wbf + 1 * 262144, hn, kx, bk, nullptr, 512, 1024, 1024, 0, SB, SB, 512, 1.f);
  gemm_kernel<false, false, true, false><<<gqkv, 256, 0, stream>>>(
      wbf + 2 * 262144, hn, v,  bv, nullptr, 512, 1024, 1024, 0, SB, SB, 512, 1.f);

  for (int c = 0; c < 1024 / NCHUNK; ++c) {
    // scores chunk: s[n_local][m] = sum_k q[k][c*256+n_local] kx[k][m] * scale
    dim3 gs(8, NCHUNK / 128, 32);
    gemm_kernel<true, false, false, false><<<gs, 256, 0, stream>>>(
        q + c * NCHUNK, kx, s, nullptr, nullptr, 1024, 1024, 1024, SB, SB, SSC, 512, scale);

    softmax_kernel<<<32 * NCHUNK, 256, 0, stream>>>(s);

    // attn-V chunk: ao[ch][c*256+n_local] = sum_m v[ch][m] attn[n_local][m]
    // attn is bf16 at the start of each fp32 score row (ld = 2048 u16).
    dim3 gav(NCHUNK / 128, 4, 32);
    gemm_kernel<false, true, true, false><<<gav, 256, 0, stream>>>(
        v, (u16*)s, hn + c * NCHUNK, nullptr, nullptr,
        1024, 2048, 1024, SB, (long)NCHUNK * 2048, SB, 1024, 1.f);
  }

  // proj + bias + residual -> fp32 d_out
  gemm_kernel<false, false, false, true><<<gqkv, 256, 0, stream>>>(
      wbf + 3 * 262144, hn, out, bp, x, 512, 1024, 1024, 0, SB, SB, 512, 1.f);
}

// Round 3
// 510.139 us; speedup vs baseline: 1.7923x; 1.7923x over previous
//
#include <hip/hip_runtime.h>
#include <hip/hip_bf16.h>

typedef unsigned short u16;
typedef __attribute__((ext_vector_type(8))) short bf16x8;
typedef __attribute__((ext_vector_type(4))) float f32x4;

#define BK 32

__device__ __forceinline__ u16 f2bf(float f) {
  union { float f; unsigned u; } a; a.f = f;
  unsigned r = a.u + 0x7fffu + ((a.u >> 16) & 1u);  // RNE
  return (u16)(r >> 16);
}

// Async-stage a [128 rows][32 u16] tile (rows stride ldg u16) into contiguous
// unpadded LDS [128][32]. global_load_lds width=16: lane i lands at base+i*16.
__device__ __forceinline__ void stage_async(const u16* __restrict__ g, int ldg,
                                            u16* __restrict__ s, int tid) {
  int lane = tid & 63, wave = tid >> 6;
#pragma unroll
  for (int t = 0; t < 2; ++t) {
    int chunk = (wave * 2 + t) * 64 + lane;        // 0..511 chunks of 16B
    int row = chunk >> 2, koff = (chunk & 3) << 3; // 4 chunks per 64B row
    __builtin_amdgcn_global_load_lds(
        (const __attribute__((address_space(1))) unsigned int*)(g + (long)row * ldg + koff),
        (__attribute__((address_space(3))) unsigned int*)(s + (wave * 2 + t) * 512),
        16, 0, 0);
  }
}

// D[m][n] = sum_k A[m][k] B[n][k]^T-style: A staged [128 m][32 k], B staged [128 n][32 k].
// TRANS_OUT: write C^T[n][m] bf16 (vectorized uint2 of 4 consecutive m).
template <bool TRANS_OUT, bool OUT_BF16, bool RESID>
__global__ __launch_bounds__(256) void gemm_kernel(
    const u16* __restrict__ Ag, const u16* __restrict__ Bg, void* __restrict__ Cg,
    const float* __restrict__ bias, const float* __restrict__ resid,
    int lda, int ldb, int ldc,
    long strideA, long strideB, long strideC, int K, float scale) {
  __shared__ u16 As[128 * BK];
  __shared__ u16 Bs[128 * BK];
  int tid = threadIdx.x;
  int b = blockIdx.z;
  int m0 = blockIdx.y * 128, n0 = blockIdx.x * 128;
  const u16* Ab = Ag + (long)b * strideA + (long)m0 * lda;
  const u16* Bb = Bg + (long)b * strideB + (long)n0 * ldb;
  int wave = tid >> 6, lane = tid & 63;
  int wr = wave >> 1, wc = wave & 1;
  int lrow = lane & 15, quad = lane >> 4;

  f32x4 acc[4][4];
#pragma unroll
  for (int i = 0; i < 4; ++i)
#pragma unroll
    for (int j = 0; j < 4; ++j) acc[i][j] = (f32x4){0.f, 0.f, 0.f, 0.f};

  for (int k0 = 0; k0 < K; k0 += BK) {
    stage_async(Ab + k0, lda, As, tid);
    stage_async(Bb + k0, ldb, Bs, tid);
    __syncthreads();  // drains vmcnt (global_load_lds) per barrier semantics
    bf16x8 af[4], bfr[4];
#pragma unroll
    for (int mt = 0; mt < 4; ++mt)
      af[mt] = *(const bf16x8*)&As[(wr * 64 + mt * 16 + lrow) * BK + quad * 8];
#pragma unroll
    for (int nt = 0; nt < 4; ++nt)
      bfr[nt] = *(const bf16x8*)&Bs[(wc * 64 + nt * 16 + lrow) * BK + quad * 8];
#pragma unroll
    for (int mt = 0; mt < 4; ++mt)
#pragma unroll
      for (int nt = 0; nt < 4; ++nt)
        acc[mt][nt] = __builtin_amdgcn_mfma_f32_16x16x32_bf16(af[mt], bfr[nt], acc[mt][nt], 0, 0, 0);
    __syncthreads();
  }

  long cbase = (long)b * strideC;
  if (TRANS_OUT) {
#pragma unroll
    for (int mt = 0; mt < 4; ++mt) {
      int rowbase = m0 + wr * 64 + mt * 16 + quad * 4;
      float4 b4 = bias ? *(const float4*)&bias[rowbase] : make_float4(0.f, 0.f, 0.f, 0.f);
#pragma unroll
      for (int nt = 0; nt < 4; ++nt) {
        int col = n0 + wc * 64 + nt * 16 + lrow;
        f32x4 a = acc[mt][nt];
        uint2 o;
        o.x = (unsigned)f2bf(a[0] * scale + b4.x) | ((unsigned)f2bf(a[1] * scale + b4.y) << 16);
        o.y = (unsigned)f2bf(a[2] * scale + b4.z) | ((unsigned)f2bf(a[3] * scale + b4.w) << 16);
        *(uint2*)((u16*)Cg + cbase + (long)col * ldc + rowbase) = o;
      }
    }
  } else {
#pragma unroll
    for (int mt = 0; mt < 4; ++mt) {
#pragma unroll
      for (int r = 0; r < 4; ++r) {
        int row = m0 + wr * 64 + mt * 16 + quad * 4 + r;
        float bv = bias ? bias[row] : 0.f;
#pragma unroll
        for (int nt = 0; nt < 4; ++nt) {
          int col = n0 + wc * 64 + nt * 16 + lrow;
          long idx = cbase + (long)row * ldc + col;
          float val = acc[mt][nt][r] * scale + bv;
          if (RESID) val += resid[idx];
          if (OUT_BF16) ((u16*)Cg)[idx] = f2bf(val);
          else ((float*)Cg)[idx] = val;
        }
      }
    }
  }
}

// One block per (group, batch): 32 channels x 1024 tokens. Writes hn TOKEN-MAJOR:
// hnT[b][token][512 ch] — each thread owns all 32 group-channels of its 4 tokens.
__global__ __launch_bounds__(256) void groupnorm_kernel(
    const float* __restrict__ x, const float* __restrict__ gamma,
    const float* __restrict__ beta, u16* __restrict__ hnT) {
  int g = blockIdx.x, b = blockIdx.y;
  const float* xb = x + ((long)b * 512 + g * 32) * 1024;
  int tid = threadIdx.x;
  float s = 0.f, sq = 0.f;
  float4 vals[32];
#pragma unroll
  for (int j = 0; j < 32; ++j) {
    float4 v = *(const float4*)(xb + (long)j * 1024 + tid * 4);
    vals[j] = v;
    s += v.x + v.y + v.z + v.w;
    sq += v.x * v.x + v.y * v.y + v.z * v.z + v.w * v.w;
  }
#pragma unroll
  for (int off = 1; off < 64; off <<= 1) {
    s += __shfl_xor(s, off);
    sq += __shfl_xor(sq, off);
  }
  __shared__ float ls[4], lq[4];
  if ((tid & 63) == 0) { ls[tid >> 6] = s; lq[tid >> 6] = sq; }
  __syncthreads();
  float ts = ls[0] + ls[1] + ls[2] + ls[3];
  float tq = lq[0] + lq[1] + lq[2] + lq[3];
  float mean = ts * (1.f / 32768.f);
  float var = tq * (1.f / 32768.f) - mean * mean;
  float rstd = rsqrtf(var + 1e-6f);
  u16* hb = hnT + (long)b * (1024 * 512) + g * 32;
#pragma unroll
  for (int t = 0; t < 4; ++t) {
    u16 row[32];
#pragma unroll
    for (int j = 0; j < 32; ++j) {
      float xv = ((const float*)&vals[j])[t];
      row[j] = f2bf((xv - mean) * rstd * gamma[g * 32 + j] + beta[g * 32 + j]);
    }
    uint4* dst = (uint4*)(hb + (long)(tid * 4 + t) * 512);
    const uint4* src = (const uint4*)row;
    dst[0] = src[0]; dst[1] = src[1]; dst[2] = src[2]; dst[3] = src[3];
  }
}

// One block per score row (1024 fp32). Writes bf16 attn in place at the row start.
__global__ __launch_bounds__(256) void softmax_kernel(float* __restrict__ s) {
  long row = blockIdx.x;
  float* sr = s + row * 1024;
  int tid = threadIdx.x;
  float4 v = *(const float4*)(sr + tid * 4);
  float m = fmaxf(fmaxf(v.x, v.y), fmaxf(v.z, v.w));
#pragma unroll
  for (int off = 1; off < 64; off <<= 1) m = fmaxf(m, __shfl_xor(m, off));
  __shared__ float lm[4], lsum[4];
  if ((tid & 63) == 0) lm[tid >> 6] = m;
  __syncthreads();
  float rowmax = fmaxf(fmaxf(lm[0], lm[1]), fmaxf(lm[2], lm[3]));
  float e0 = expf(v.x - rowmax), e1 = expf(v.y - rowmax);
  float e2 = expf(v.z - rowmax), e3 = expf(v.w - rowmax);
  float sum = e0 + e1 + e2 + e3;
#pragma unroll
  for (int off = 1; off < 64; off <<= 1) sum += __shfl_xor(sum, off);
  if ((tid & 63) == 0) lsum[tid >> 6] = sum;
  __syncthreads();
  float inv = 1.f / (lsum[0] + lsum[1] + lsum[2] + lsum[3]);
  uint2 o;
  o.x = (unsigned)f2bf(e0 * inv) | ((unsigned)f2bf(e1 * inv) << 16);
  o.y = (unsigned)f2bf(e2 * inv) | ((unsigned)f2bf(e3 * inv) << 16);
  *(uint2*)((u16*)sr + tid * 4) = o;
}

// Convert the 4 weight matrices (512x512 fp32) to bf16, packed contiguously.
__global__ __launch_bounds__(256) void convertw_kernel(
    const float* __restrict__ w0, const float* __restrict__ w1,
    const float* __restrict__ w2, const float* __restrict__ w3,
    u16* __restrict__ out) {
  int wsel = blockIdx.x >> 8;
  const float* src = wsel == 0 ? w0 : wsel == 1 ? w1 : wsel == 2 ? w2 : w3;
  int idx = ((blockIdx.x & 255) * 256 + threadIdx.x) * 4;
  float4 v = *(const float4*)(src + idx);
  uint2 o;
  o.x = (unsigned)f2bf(v.x) | ((unsigned)f2bf(v.y) << 16);
  o.y = (unsigned)f2bf(v.z) | ((unsigned)f2bf(v.w) << 16);
  *(uint2*)(out + (long)wsel * 262144 + idx) = o;
}

extern "C" void kernel_launch(void* const* d_in, const int* in_sizes, int n_in,
                              void* d_out, int out_size, void* d_ws, size_t ws_size,
                              hipStream_t stream) {
  const float* x     = (const float*)d_in[0];
  const float* gamma = (const float*)d_in[1];
  const float* beta  = (const float*)d_in[2];
  const float* wq    = (const float*)d_in[3];
  const float* bq    = (const float*)d_in[4];
  const float* wk    = (const float*)d_in[5];
  const float* bk    = (const float*)d_in[6];
  const float* wv    = (const float*)d_in[7];
  const float* bv    = (const float*)d_in[8];
  const float* wp    = (const float*)d_in[9];
  const float* bp    = (const float*)d_in[10];
  float* out = (float*)d_out;
  char* ws = (char*)d_ws;

  // Workspace (194 MB): all activations token-major except v.
  u16* wbf = (u16*)ws;                      //   2 MB: wq|wk|wv|wp bf16 [o][c]
  u16* hnT = (u16*)(ws + (2L << 20));       //  32 MB: [b][n][c]  (reused for aoT)
  u16* qT  = (u16*)(ws + (34L << 20));      //  32 MB: [b][n][c]
  u16* kT  = (u16*)(ws + (66L << 20));      //  32 MB: [b][m][c]
  u16* v   = (u16*)(ws + (98L << 20));      //  32 MB: [b][c][m]
  float* s = (float*)(ws + (130L << 20));   //  64 MB: [b][512 n][1024 m] fp32 chunk
  u16* aoT = hnT;                           //  reuse: [b][n][c]

  const long SB = 512L * 1024;   // per-batch element stride of all (512x1024) tensors
  const float scale = 0.044194173824159216f;  // 512^-0.5
  const int NCHUNK = 512;
  const long SSC = (long)NCHUNK * 1024;  // per-batch fp32 score-chunk stride

  convertw_kernel<<<1024, 256, 0, stream>>>(wq, wk, wv, wp, wbf);
  groupnorm_kernel<<<dim3(16, 32), 256, 0, stream>>>(x, gamma, beta, hnT);

  // QKV: A=W[o][c] (lda=512), B=hnT[n][c] (ldb=512), K=512.
  dim3 gqkv(8, 4, 32);  // n-tiles, o-tiles, batch
  gemm_kernel<true, true, false><<<gqkv, 256, 0, stream>>>(
      wbf + 0 * 262144, hnT, qT, bq, nullptr, 512, 512, 512, 0, SB, SB, 512, 1.f);
  gemm_kernel<true, true, false><<<gqkv, 256, 0, stream>>>(
      wbf + 1 * 262144, hnT, kT, bk, nullptr, 512, 512, 512, 0, SB, SB, 512, 1.f);
  gemm_kernel<false, true, false><<<gqkv, 256, 0, stream>>>(
      wbf + 2 * 262144, hnT, v, bv, nullptr, 512, 512, 1024, 0, SB, SB, 512, 1.f);

  for (int c = 0; c < 1024 / NCHUNK; ++c) {
    // scores: s[n_local][m] = sum_c qT[c*NC+n_local][ch] kT[m][ch] * scale
    dim3 gs(8, NCHUNK / 128, 32);
    gemm_kernel<false, false, false><<<gs, 256, 0, stream>>>(
        qT + (long)c * NCHUNK * 512, kT, s, nullptr, nullptr,
        512, 512, 1024, SB, SB, SSC, 512, scale);

    softmax_kernel<<<32 * NCHUNK, 256, 0, stream>>>(s);

    // attn-V: ao[ch][n_local] = sum_m v[ch][m] attn[n_local][m]; write aoT[n][ch].
    // attn rows are bf16 at the head of each fp32 score row (ldb = 2048 u16).
    dim3 gav(NCHUNK / 128, 4, 32);
    gemm_kernel<true, true, false><<<gav, 256, 0, stream>>>(
        v, (u16*)s, aoT + (long)c * NCHUNK * 512, nullptr, nullptr,
        1024, 2048, 512, SB, (long)NCHUNK * 2048, SB, 1024, 1.f);
  }

  // proj: A=wp[o][c], B=aoT[n][c]; out natural fp32 + bias + residual.
  gemm_kernel<false, false, true><<<gqkv, 256, 0, stream>>>(
      wbf + 3 * 262144, aoT, out, bp, x, 512, 512, 1024, 0, SB, SB, 512, 1.f);
}

// Round 4
// 423.325 us; speedup vs baseline: 2.1598x; 1.2051x over previous
//
#include <hip/hip_runtime.h>
#include <hip/hip_bf16.h>

typedef unsigned short u16;
typedef __attribute__((ext_vector_type(8))) short bf16x8;
typedef __attribute__((ext_vector_type(4))) float f32x4;

#define BK 32
#define TILE_ELEMS (128 * BK)

__device__ __forceinline__ u16 f2bf(float f) {
  union { float f; unsigned u; } a; a.f = f;
  unsigned r = a.u + 0x7fffu + ((a.u >> 16) & 1u);  // RNE
  return (u16)(r >> 16);
}

__device__ __forceinline__ u16 f2h(float f) {
  union { _Float16 h; u16 u; } c; c.h = (_Float16)f; return c.u;
}

// Async-stage a [128 rows][32 u16] tile (row stride ldg u16) into contiguous
// unpadded LDS [128][32]. global_load_lds width=16: lane i lands at base+i*16.
__device__ __forceinline__ void stage_async(const u16* __restrict__ g, int ldg,
                                            u16* __restrict__ s, int tid) {
  int lane = tid & 63, wave = tid >> 6;
#pragma unroll
  for (int t = 0; t < 2; ++t) {
    int chunk = (wave * 2 + t) * 64 + lane;        // 0..511 chunks of 16B
    int row = chunk >> 2, koff = (chunk & 3) << 3; // 4 chunks per 64B row
    __builtin_amdgcn_global_load_lds(
        (const __attribute__((address_space(1))) unsigned int*)(g + (long)row * ldg + koff),
        (__attribute__((address_space(3))) unsigned int*)(s + (wave * 2 + t) * 512),
        16, 0, 0);
  }
}

// Double-buffered K-loop: one barrier per iter; next tile's async loads issued
// right after the barrier so the next barrier's vmcnt-drain waits on old loads.
__device__ __forceinline__ void gemm_core(
    const u16* __restrict__ Ab, const u16* __restrict__ Bb,
    int lda, int ldb, int K, int tid,
    u16* __restrict__ As, u16* __restrict__ Bs, f32x4 (&acc)[4][4]) {
  int wave = tid >> 6, lane = tid & 63;
  int wr = wave >> 1, wc = wave & 1;
  int lrow = lane & 15, quad = lane >> 4;
#pragma unroll
  for (int i = 0; i < 4; ++i)
#pragma unroll
    for (int j = 0; j < 4; ++j) acc[i][j] = (f32x4){0.f, 0.f, 0.f, 0.f};
  stage_async(Ab, lda, As, tid);
  stage_async(Bb, ldb, Bs, tid);
  int cur = 0;
  for (int k0 = 0; k0 < K; k0 += BK) {
    __syncthreads();  // drains vmcnt (buf[cur] ready) + lgkmcnt (old reads done)
    if (k0 + BK < K) {
      stage_async(Ab + k0 + BK, lda, As + (cur ^ 1) * TILE_ELEMS, tid);
      stage_async(Bb + k0 + BK, ldb, Bs + (cur ^ 1) * TILE_ELEMS, tid);
    }
    const u16* Ac = As + cur * TILE_ELEMS;
    const u16* Bc = Bs + cur * TILE_ELEMS;
    bf16x8 af[4], bfr[4];
#pragma unroll
    for (int mt = 0; mt < 4; ++mt)
      af[mt] = *(const bf16x8*)&Ac[(wr * 64 + mt * 16 + lrow) * BK + quad * 8];
#pragma unroll
    for (int nt = 0; nt < 4; ++nt)
      bfr[nt] = *(const bf16x8*)&Bc[(wc * 64 + nt * 16 + lrow) * BK + quad * 8];
#pragma unroll
    for (int mt = 0; mt < 4; ++mt)
#pragma unroll
      for (int nt = 0; nt < 4; ++nt)
        acc[mt][nt] = __builtin_amdgcn_mfma_f32_16x16x32_bf16(af[mt], bfr[nt], acc[mt][nt], 0, 0, 0);
    cur ^= 1;
  }
}

// Transposed bf16 epilogue: write C^T[col][rowbase..+3] as one uint2 (4 bf16).
__device__ __forceinline__ void epi_trans_bf16(
    f32x4 (&acc)[4][4], u16* __restrict__ C, long cbase, int m0, int n0, int ldc,
    const float* __restrict__ bias, float scale, int tid) {
  int wave = tid >> 6, lane = tid & 63;
  int wr = wave >> 1, wc = wave & 1;
  int lrow = lane & 15, quad = lane >> 4;
#pragma unroll
  for (int mt = 0; mt < 4; ++mt) {
    int rowbase = m0 + wr * 64 + mt * 16 + quad * 4;
    float4 b4 = bias ? *(const float4*)&bias[rowbase] : make_float4(0.f, 0.f, 0.f, 0.f);
#pragma unroll
    for (int nt = 0; nt < 4; ++nt) {
      int col = n0 + wc * 64 + nt * 16 + lrow;
      f32x4 a = acc[mt][nt];
      uint2 o;
      o.x = (unsigned)f2bf(a[0] * scale + b4.x) | ((unsigned)f2bf(a[1] * scale + b4.y) << 16);
      o.y = (unsigned)f2bf(a[2] * scale + b4.z) | ((unsigned)f2bf(a[3] * scale + b4.w) << 16);
      *(uint2*)(C + cbase + (long)col * ldc + rowbase) = o;
    }
  }
}

// MODE: 0 = TRANS bf16 (attnV->aoT), 1 = natural fp16 (scores),
//       2 = natural fp32 + bias + residual (proj), 3 = merged QKV.
template <int MODE>
__global__ __launch_bounds__(256) void gemm_kernel(
    const u16* __restrict__ Ag, const u16* __restrict__ Bg,
    void* __restrict__ C0, void* __restrict__ C1, void* __restrict__ C2,
    const float* __restrict__ bias0, const float* __restrict__ bias1,
    const float* __restrict__ bias2, const float* __restrict__ resid,
    int lda, int ldb, int ldc,
    long strideA, long strideB, long strideC, int K, float scale) {
  __shared__ u16 As[2 * TILE_ELEMS];
  __shared__ u16 Bs[2 * TILE_ELEMS];
  int tid = threadIdx.x;
  int b = blockIdx.z;
  int m0 = blockIdx.y * 128, n0 = blockIdx.x * 128;
  const u16* Ab = Ag + (long)b * strideA + (long)m0 * lda;
  const u16* Bb = Bg + (long)b * strideB + (long)n0 * ldb;
  f32x4 acc[4][4];
  gemm_core(Ab, Bb, lda, ldb, K, tid, As, Bs, acc);

  int wave = tid >> 6, lane = tid & 63;
  int wr = wave >> 1, wc = wave & 1;
  int lrow = lane & 15, quad = lane >> 4;
  long cbase = (long)b * strideC;

  if (MODE == 0) {
    epi_trans_bf16(acc, (u16*)C0, cbase, m0, n0, ldc, bias0, scale, tid);
  } else if (MODE == 1) {
#pragma unroll
    for (int mt = 0; mt < 4; ++mt)
#pragma unroll
      for (int r = 0; r < 4; ++r) {
        int row = m0 + wr * 64 + mt * 16 + quad * 4 + r;
#pragma unroll
        for (int nt = 0; nt < 4; ++nt) {
          int col = n0 + wc * 64 + nt * 16 + lrow;
          ((u16*)C0)[cbase + (long)row * ldc + col] = f2h(acc[mt][nt][r] * scale);
        }
      }
  } else if (MODE == 2) {
#pragma unroll
    for (int mt = 0; mt < 4; ++mt)
#pragma unroll
      for (int r = 0; r < 4; ++r) {
        int row = m0 + wr * 64 + mt * 16 + quad * 4 + r;
        float bv = bias0[row];
#pragma unroll
        for (int nt = 0; nt < 4; ++nt) {
          int col = n0 + wc * 64 + nt * 16 + lrow;
          long idx = cbase + (long)row * ldc + col;
          ((float*)C0)[idx] = acc[mt][nt][r] * scale + bv + resid[idx];
        }
      }
  } else {  // MODE 3: merged QKV. Segments of 512 A-rows: q (trans), k (trans), v (natural bf16)
    int seg = m0 >> 9;
    int ml = m0 & 511;
    if (seg == 0) {
      epi_trans_bf16(acc, (u16*)C0, cbase, ml, n0, 512, bias0, 1.f, tid);
    } else if (seg == 1) {
      epi_trans_bf16(acc, (u16*)C1, cbase, ml, n0, 512, bias1, 1.f, tid);
    } else {
#pragma unroll
      for (int mt = 0; mt < 4; ++mt)
#pragma unroll
        for (int r = 0; r < 4; ++r) {
          int row = ml + wr * 64 + mt * 16 + quad * 4 + r;
          float bv = bias2[row];
#pragma unroll
          for (int nt = 0; nt < 4; ++nt) {
            int col = n0 + wc * 64 + nt * 16 + lrow;
            ((u16*)C2)[cbase + (long)row * 1024 + col] = f2bf(acc[mt][nt][r] + bv);
          }
        }
    }
  }
}

// One block per (group, batch): 32 channels x 1024 tokens. Writes hn TOKEN-MAJOR.
__global__ __launch_bounds__(256) void groupnorm_kernel(
    const float* __restrict__ x, const float* __restrict__ gamma,
    const float* __restrict__ beta, u16* __restrict__ hnT) {
  int g = blockIdx.x, b = blockIdx.y;
  const float* xb = x + ((long)b * 512 + g * 32) * 1024;
  int tid = threadIdx.x;
  float s = 0.f, sq = 0.f;
  float4 vals[32];
#pragma unroll
  for (int j = 0; j < 32; ++j) {
    float4 v = *(const float4*)(xb + (long)j * 1024 + tid * 4);
    vals[j] = v;
    s += v.x + v.y + v.z + v.w;
    sq += v.x * v.x + v.y * v.y + v.z * v.z + v.w * v.w;
  }
#pragma unroll
  for (int off = 1; off < 64; off <<= 1) {
    s += __shfl_xor(s, off);
    sq += __shfl_xor(sq, off);
  }
  __shared__ float ls[4], lq[4];
  if ((tid & 63) == 0) { ls[tid >> 6] = s; lq[tid >> 6] = sq; }
  __syncthreads();
  float ts = ls[0] + ls[1] + ls[2] + ls[3];
  float tq = lq[0] + lq[1] + lq[2] + lq[3];
  float mean = ts * (1.f / 32768.f);
  float var = tq * (1.f / 32768.f) - mean * mean;
  float rstd = rsqrtf(var + 1e-6f);
  u16* hb = hnT + (long)b * (1024 * 512) + g * 32;
#pragma unroll
  for (int t = 0; t < 4; ++t) {
    u16 row[32];
#pragma unroll
    for (int j = 0; j < 32; ++j) {
      float xv = ((const float*)&vals[j])[t];
      row[j] = f2bf((xv - mean) * rstd * gamma[g * 32 + j] + beta[g * 32 + j]);
    }
    uint4* dst = (uint4*)(hb + (long)(tid * 4 + t) * 512);
    const uint4* src = (const uint4*)row;
    dst[0] = src[0]; dst[1] = src[1]; dst[2] = src[2]; dst[3] = src[3];
  }
}

// One block per score row (1024 fp16). Writes bf16 attn in place (full row).
__global__ __launch_bounds__(256) void softmax_kernel(u16* __restrict__ s) {
  long row = blockIdx.x;
  u16* sr = s + row * 1024;
  int tid = threadIdx.x;
  union { uint2 u; _Float16 h[4]; } c;
  c.u = *(const uint2*)(sr + tid * 4);
  float v0 = (float)c.h[0], v1 = (float)c.h[1], v2 = (float)c.h[2], v3 = (float)c.h[3];
  float m = fmaxf(fmaxf(v0, v1), fmaxf(v2, v3));
#pragma unroll
  for (int off = 1; off < 64; off <<= 1) m = fmaxf(m, __shfl_xor(m, off));
  __shared__ float lm[4], lsum[4];
  if ((tid & 63) == 0) lm[tid >> 6] = m;
  __syncthreads();
  float rowmax = fmaxf(fmaxf(lm[0], lm[1]), fmaxf(lm[2], lm[3]));
  float e0 = expf(v0 - rowmax), e1 = expf(v1 - rowmax);
  float e2 = expf(v2 - rowmax), e3 = expf(v3 - rowmax);
  float sum = e0 + e1 + e2 + e3;
#pragma unroll
  for (int off = 1; off < 64; off <<= 1) sum += __shfl_xor(sum, off);
  if ((tid & 63) == 0) lsum[tid >> 6] = sum;
  __syncthreads();
  float inv = 1.f / (lsum[0] + lsum[1] + lsum[2] + lsum[3]);
  uint2 o;
  o.x = (unsigned)f2bf(e0 * inv) | ((unsigned)f2bf(e1 * inv) << 16);
  o.y = (unsigned)f2bf(e2 * inv) | ((unsigned)f2bf(e3 * inv) << 16);
  *(uint2*)(sr + tid * 4) = o;
}

// Convert the 4 weight matrices (512x512 fp32) to bf16, packed contiguously.
__global__ __launch_bounds__(256) void convertw_kernel(
    const float* __restrict__ w0, const float* __restrict__ w1,
    const float* __restrict__ w2, const float* __restrict__ w3,
    u16* __restrict__ out) {
  int wsel = blockIdx.x >> 8;
  const float* src = wsel == 0 ? w0 : wsel == 1 ? w1 : wsel == 2 ? w2 : w3;
  int idx = ((blockIdx.x & 255) * 256 + threadIdx.x) * 4;
  float4 v = *(const float4*)(src + idx);
  uint2 o;
  o.x = (unsigned)f2bf(v.x) | ((unsigned)f2bf(v.y) << 16);
  o.y = (unsigned)f2bf(v.z) | ((unsigned)f2bf(v.w) << 16);
  *(uint2*)(out + (long)wsel * 262144 + idx) = o;
}

extern "C" void kernel_launch(void* const* d_in, const int* in_sizes, int n_in,
                              void* d_out, int out_size, void* d_ws, size_t ws_size,
                              hipStream_t stream) {
  const float* x     = (const float*)d_in[0];
  const float* gamma = (const float*)d_in[1];
  const float* beta  = (const float*)d_in[2];
  const float* wq    = (const float*)d_in[3];
  const float* bq    = (const float*)d_in[4];
  const float* wk    = (const float*)d_in[5];
  const float* bk    = (const float*)d_in[6];
  const float* wv    = (const float*)d_in[7];
  const float* bv    = (const float*)d_in[8];
  const float* wp    = (const float*)d_in[9];
  const float* bp    = (const float*)d_in[10];
  float* out = (float*)d_out;
  char* ws = (char*)d_ws;

  // Workspace (194 MB)
  u16* wbf = (u16*)ws;                      //   2 MB: wq|wk|wv|wp bf16 [o][c], packed
  u16* hnT = (u16*)(ws + (2L << 20));       //  32 MB: [b][n][c]  (reused for aoT)
  u16* qT  = (u16*)(ws + (34L << 20));      //  32 MB: [b][n][c]
  u16* kT  = (u16*)(ws + (66L << 20));      //  32 MB: [b][m][c]
  u16* v   = (u16*)(ws + (98L << 20));      //  32 MB: [b][c][m]
  u16* s16 = (u16*)(ws + (130L << 20));     //  64 MB: [b][n][m] fp16 scores / bf16 attn
  u16* aoT = hnT;

  const long SB = 512L * 1024;        // per-batch element stride of 512x1024 tensors
  const long SS = 1024L * 1024;       // per-batch element stride of scores (u16)
  const float scale = 0.044194173824159216f;  // 512^-0.5

  convertw_kernel<<<1024, 256, 0, stream>>>(wq, wk, wv, wp, wbf);
  groupnorm_kernel<<<dim3(16, 32), 256, 0, stream>>>(x, gamma, beta, hnT);

  // Merged QKV: A = [wq;wk;wv] (1536x512), B = hnT [n][c]. q,k -> token-major; v natural.
  gemm_kernel<3><<<dim3(8, 12, 32), 256, 0, stream>>>(
      wbf, hnT, qT, kT, v, bq, bk, bv, nullptr,
      512, 512, 0, 0, SB, SB, 512, 1.f);

  // Scores: s[n][m] = qT[n][:] . kT[m][:] * scale -> fp16, full (no chunking).
  gemm_kernel<1><<<dim3(8, 8, 32), 256, 0, stream>>>(
      qT, kT, s16, nullptr, nullptr, nullptr, nullptr, nullptr, nullptr,
      512, 512, 1024, SB, SB, SS, 512, scale);

  softmax_kernel<<<32 * 1024, 256, 0, stream>>>(s16);

  // attn-V: aoT[n][c] = sum_m v[c][m] attn[n][m] (A = v, B = attn bf16 ld 1024).
  gemm_kernel<0><<<dim3(8, 4, 32), 256, 0, stream>>>(
      v, s16, aoT, nullptr, nullptr, nullptr, nullptr, nullptr, nullptr,
      1024, 1024, 512, SB, SS, SB, 1024, 1.f);

  // Proj + bias + residual -> fp32 d_out (natural [c][n]).
  gemm_kernel<2><<<dim3(8, 4, 32), 256, 0, stream>>>(
      wbf + 3 * 262144, aoT, out, nullptr, nullptr, bp, nullptr, nullptr, x,
      512, 512, 1024, 0, SB, SB, 512, 1.f);
}